// Round 6
// baseline (628.752 us; speedup 1.0000x reference)
//
#include <hip/hip_runtime.h>
#include <hip/hip_bf16.h>

#define N_NODES 100000
#define N_EDGES 1000000
#define DIM 64
#define N_GRAPHS 256
#define F_IN 4
#define F_OUT 4
#define SCAN_CHUNK 2048  // 256 threads x 8

__device__ __forceinline__ float bf_lo(unsigned int u) { return __uint_as_float(u << 16); }
__device__ __forceinline__ float bf_hi(unsigned int u) { return __uint_as_float(u & 0xffff0000u); }
__device__ __forceinline__ unsigned short f2bf(float f) {
    unsigned int u = __float_as_uint(f);
    u = u + 0x7fffu + ((u >> 16) & 1u);  // RTNE
    return (unsigned short)(u >> 16);
}

// ---------------- degree ----------------
__global__ void deg_kernel(const int* __restrict__ cols, int* __restrict__ deg, int E) {
    int e = blockIdx.x * 256 + threadIdx.x;
    if (e < E) atomicAdd(&deg[cols[e]], 1);
}

// ---------------- dis + packed xsp = {dis*x[0..3], dis, pad3} (32B rows) ----------------
__global__ void dis_xs_kernel(const int* __restrict__ deg, const float* __restrict__ x,
                              float* __restrict__ dis, float* __restrict__ xsp, int n) {
    int i = blockIdx.x * 256 + threadIdx.x;
    if (i >= n) return;
    float d = 1.0f / sqrtf((float)(deg[i] + 1));  // +1 for self loop
    dis[i] = d;
    float4 xi = ((const float4*)x)[i];
    ((float4*)xsp)[2 * i] = make_float4(d * xi.x, d * xi.y, d * xi.z, d * xi.w);
    ((float4*)xsp)[2 * i + 1] = make_float4(d, 0.f, 0.f, 0.f);
}

// ---------------- CSR build ----------------
__global__ void scan_local(const int* __restrict__ deg, int* __restrict__ rowptr,
                           int* __restrict__ blockSums, int n) {
    __shared__ int sh[256];
    int b = blockIdx.x, t = threadIdx.x;
    int base = b * SCAN_CHUNK + t * 8;
    int v[8];
    int s = 0;
#pragma unroll
    for (int i = 0; i < 8; ++i) {
        int idx = base + i;
        int d = (idx < n) ? deg[idx] : 0;
        v[i] = s;
        s += d;
    }
    sh[t] = s;
    __syncthreads();
    for (int ofs = 1; ofs < 256; ofs <<= 1) {
        int u = (t >= ofs) ? sh[t - ofs] : 0;
        __syncthreads();
        sh[t] += u;
        __syncthreads();
    }
    int texcl = sh[t] - s;
#pragma unroll
    for (int i = 0; i < 8; ++i) {
        int idx = base + i;
        if (idx < n) rowptr[idx] = texcl + v[i];
    }
    if (t == 255) blockSums[b] = sh[255];
}

__global__ void scan_blocks(const int* __restrict__ blockSums, int* __restrict__ blockOffs, int nb) {
    int t = threadIdx.x;  // single wave of 64, nb <= 64
    int orig = (t < nb) ? blockSums[t] : 0;
    int v = orig;
    for (int ofs = 1; ofs < 64; ofs <<= 1) {
        int u = __shfl_up(v, ofs, 64);
        if (t >= ofs) v += u;
    }
    if (t < nb) blockOffs[t] = v - orig;  // exclusive
}

__global__ void add_offsets(int* __restrict__ rowptr, int* __restrict__ cursor,
                            const int* __restrict__ blockOffs, int n) {
    int i = blockIdx.x * 256 + threadIdx.x;
    if (i < n) {
        int v = rowptr[i] + blockOffs[i >> 11];  // SCAN_CHUNK = 2048
        rowptr[i] = v;
        cursor[i] = v;
    }
    if (i == 0) rowptr[n] = N_EDGES;
}

__global__ void fill_csr(const int* __restrict__ rows, const int* __restrict__ cols,
                         int* __restrict__ cursor, int* __restrict__ csr_src, int E) {
    int e = blockIdx.x * 256 + threadIdx.x;
    if (e >= E) return;
    int c = cols[e], r = rows[e];
    int pos = atomicAdd(&cursor[c], 1);
    csr_src[pos] = r;
}

// ---------------- layer-0 aggregation: 4 lanes per node, x2 unroll ----------------
__global__ __launch_bounds__(256, 8)
void csr_agg_x(const int* __restrict__ rowptr, const int* __restrict__ csr_src,
               const float* __restrict__ xsp, float* __restrict__ aggx,
               float* __restrict__ normsum, int n) {
    int t = blockIdx.x * 256 + threadIdx.x;
    int c = t >> 2, sl = t & 3;
    if (c >= n) return;
    const float4* p = (const float4*)xsp;
    int s = rowptr[c], e = rowptr[c + 1];
    float4 a = make_float4(0.f, 0.f, 0.f, 0.f);
    float ns = 0.f;
    float dc = p[2 * c + 1].x;
    if (sl == 0) { a = p[2 * c]; ns = dc; }  // self contribution
    int k = s + sl;
    for (; k + 4 < e; k += 8) {
        int r1 = csr_src[k], r2 = csr_src[k + 4];
        float4 v1 = p[2 * r1];
        float n1 = p[2 * r1 + 1].x;
        float4 v2 = p[2 * r2];
        float n2 = p[2 * r2 + 1].x;
        a.x += v1.x + v2.x; a.y += v1.y + v2.y; a.z += v1.z + v2.z; a.w += v1.w + v2.w;
        ns += n1 + n2;
    }
    if (k < e) {
        int r = csr_src[k];
        float4 v = p[2 * r];
        a.x += v.x; a.y += v.y; a.z += v.z; a.w += v.w;
        ns += p[2 * r + 1].x;
    }
#pragma unroll
    for (int m = 1; m < 4; m <<= 1) {
        a.x += __shfl_xor(a.x, m, 64);
        a.y += __shfl_xor(a.y, m, 64);
        a.z += __shfl_xor(a.z, m, 64);
        a.w += __shfl_xor(a.w, m, 64);
        ns += __shfl_xor(ns, m, 64);
    }
    if (sl == 0) {
        ((float4*)aggx)[c] = make_float4(dc * a.x, dc * a.y, dc * a.z, dc * a.w);
        normsum[c] = dc * ns;
    }
}

// ---------------- fused lin0+lin1 -> bf16 hs1 ----------------
__global__ __launch_bounds__(256, 4)
void lin01_kernel(const float* __restrict__ aggx, const float* __restrict__ normsum,
                  const float* __restrict__ dis, const float* __restrict__ W0,
                  const float* __restrict__ b0, const float* __restrict__ W1,
                  const float* __restrict__ b1, unsigned short* __restrict__ out, int n) {
    int tid = threadIdx.x;
    int wid = tid >> 6, j = tid & 63;
    float w0c[4];
#pragma unroll
    for (int k = 0; k < 4; ++k) w0c[k] = W0[k * 64 + j];
    float b0j = b0[j];
    float w1c[64];
#pragma unroll
    for (int k = 0; k < 64; ++k) w1c[k] = W1[k * 64 + j];
    float b1j = b1[j];
    int rowBase = blockIdx.x * 16 + wid * 4;
#pragma unroll 1
    for (int i = 0; i < 4; ++i) {
        int row = rowBase + i;
        if (row >= n) return;
        float4 ax = ((const float4*)aggx)[row];
        float ns = normsum[row];
        float g = ns * b0j + ax.x * w0c[0] + ax.y * w0c[1] + ax.z * w0c[2] + ax.w * w0c[3];
        float t = tanhf(g);
        float o = b1j;
#pragma unroll
        for (int k = 0; k < 64; ++k) o += __shfl(t, k, 64) * w1c[k];
        out[row * 64 + j] = f2bf(dis[row] * o);
    }
}

// ---------------- fused agg (bf16 rows) + linear, wave-independent, barrier-free ----------------
// gcn = dc*(sum hs + self); act = (topo*)tanh(gcn); out = act@W + b (x dc if BF16_OUT)
template <bool TOPO, bool BF16_OUT>
__global__ __launch_bounds__(256, 6)
void fused_agg_lin(const int* __restrict__ rowptr, const int* __restrict__ csr_src,
                   const float* __restrict__ dis, const uint2* __restrict__ hs,
                   const float* __restrict__ topo, const float* __restrict__ W,
                   const float* __restrict__ b, void* __restrict__ outv) {
    __shared__ float sh[4][64];  // wave-private slice: no block barrier needed
    int tid = threadIdx.x;
    int wid = tid >> 6, lane = tid & 63;
    int q = lane >> 4, f = lane & 15;  // 4 edge slots x 16 lanes (8B each -> 128B row)
    float wcol[64];
#pragma unroll
    for (int k = 0; k < 64; ++k) wcol[k] = W[k * 64 + lane];
    float bj = b[lane];
    int nodeBase = blockIdx.x * 16 + wid * 4;  // grid*16 == N exactly
#pragma unroll 1
    for (int i = 0; i < 4; ++i) {
        int node = nodeBase + i;
        float dc = dis[node];
        int s = rowptr[node], e = rowptr[node + 1];
        float a0 = 0.f, a1 = 0.f, a2 = 0.f, a3 = 0.f;
        float c0 = 0.f, c1 = 0.f, c2 = 0.f, c3 = 0.f;
        if (q == 0) {  // self row (hs pre-scaled by dis)
            uint2 u = hs[node * 16 + f];
            a0 = bf_lo(u.x); a1 = bf_hi(u.x); a2 = bf_lo(u.y); a3 = bf_hi(u.y);
        }
        int k = s + q;
        for (; k + 4 < e; k += 8) {  // x2 unroll: 8 rows in flight per wave
            int r1 = csr_src[k];
            int r2 = csr_src[k + 4];
            uint2 u1 = hs[r1 * 16 + f];
            uint2 u2 = hs[r2 * 16 + f];
            a0 += bf_lo(u1.x); a1 += bf_hi(u1.x); a2 += bf_lo(u1.y); a3 += bf_hi(u1.y);
            c0 += bf_lo(u2.x); c1 += bf_hi(u2.x); c2 += bf_lo(u2.y); c3 += bf_hi(u2.y);
        }
        if (k < e) {
            int r = csr_src[k];
            uint2 u = hs[r * 16 + f];
            a0 += bf_lo(u.x); a1 += bf_hi(u.x); a2 += bf_lo(u.y); a3 += bf_hi(u.y);
        }
        a0 += c0; a1 += c1; a2 += c2; a3 += c3;
#pragma unroll
        for (int m = 16; m < 64; m <<= 1) {
            a0 += __shfl_xor(a0, m, 64);
            a1 += __shfl_xor(a1, m, 64);
            a2 += __shfl_xor(a2, m, 64);
            a3 += __shfl_xor(a3, m, 64);
        }
        if (q == 0) {
            float4 v;
            v.x = tanhf(dc * a0);
            v.y = tanhf(dc * a1);
            v.z = tanhf(dc * a2);
            v.w = tanhf(dc * a3);
            if (TOPO) {
                float4 tp = ((const float4*)topo)[node * 16 + f];
                v.x *= tp.x; v.y *= tp.y; v.z *= tp.z; v.w *= tp.w;
            }
            ((float4*)sh[wid])[f] = v;
        }
        // intra-wave ds_write -> ds_read: ordered via lgkmcnt, no __syncthreads
        float o = bj;
        const float4* shr = (const float4*)sh[wid];
#pragma unroll
        for (int kq = 0; kq < 16; ++kq) {
            float4 v = shr[kq];
            o += v.x * wcol[4 * kq] + v.y * wcol[4 * kq + 1] +
                 v.z * wcol[4 * kq + 2] + v.w * wcol[4 * kq + 3];
        }
        if (BF16_OUT)
            ((unsigned short*)outv)[node * 64 + lane] = f2bf(dc * o);
        else
            ((float*)outv)[node * 64 + lane] = o;
    }
}

// ---------------- per-graph pooling (contiguous sorted batch vector) ----------------
__global__ void pool_kernel(const float* __restrict__ hf, float* __restrict__ pooled, int n, int G) {
    int g = blockIdx.x;
    int start = (int)(((long long)g * n + G - 1) / G);
    int end = (int)(((long long)(g + 1) * n + G - 1) / G);
    int tid = threadIdx.x;
    int nd = tid >> 6, j = tid & 63;
    float mx = -INFINITY, sm = 0.f;
    for (int i = start + nd; i < end; i += 4) {
        float v = hf[i * 64 + j];
        mx = fmaxf(mx, v);
        sm += v;
    }
    __shared__ float smx[256];
    __shared__ float ssm[256];
    smx[tid] = mx;
    ssm[tid] = sm;
    __syncthreads();
    if (nd == 0) {
        mx = fmaxf(fmaxf(smx[j], smx[64 + j]), fmaxf(smx[128 + j], smx[192 + j]));
        sm = ssm[j] + ssm[64 + j] + ssm[128 + j] + ssm[192 + j];
        float cnt = (float)(end - start);
        pooled[g * 128 + j] = mx;
        pooled[g * 128 + 64 + j] = sm / cnt;
    }
}

// ---------------- output GEMM ----------------
__global__ void out_kernel(const float* __restrict__ pooled, const float* __restrict__ Wo,
                           const float* __restrict__ bo, float* __restrict__ out, int G) {
    int tid = blockIdx.x * blockDim.x + threadIdx.x;
    if (tid >= G * F_OUT) return;
    int g = tid >> 2, o = tid & 3;
    float acc = bo[o];
#pragma unroll 8
    for (int k = 0; k < 2 * DIM; ++k) acc += pooled[g * 2 * DIM + k] * Wo[k * F_OUT + o];
    out[g * F_OUT + o] = acc;
}

extern "C" void kernel_launch(void* const* d_in, const int* in_sizes, int n_in,
                              void* d_out, int out_size, void* d_ws, size_t ws_size,
                              hipStream_t stream) {
    const float* x = (const float*)d_in[0];
    const int* edge_index = (const int*)d_in[1];
    const float* topo = (const float*)d_in[3];
    const float* W0 = (const float*)d_in[4];
    const float* b0 = (const float*)d_in[5];
    const float* W1 = (const float*)d_in[6];
    const float* b1 = (const float*)d_in[7];
    const float* W2 = (const float*)d_in[8];
    const float* b2 = (const float*)d_in[9];
    const float* W3 = (const float*)d_in[10];
    const float* b3 = (const float*)d_in[11];
    const float* Wf = (const float*)d_in[12];
    const float* bf_ = (const float*)d_in[13];
    const float* Wo = (const float*)d_in[14];
    const float* bo = (const float*)d_in[15];

    const int* rows = edge_index;            // sources
    const int* cols = edge_index + N_EDGES;  // targets

    const int numScanBlocks = (N_NODES + SCAN_CHUNK - 1) / SCAN_CHUNK;  // 49

    // workspace layout
    char* ws = (char*)d_ws;
    size_t off = 0;
    int* deg = (int*)(ws + off); off += (size_t)N_NODES * 4;
    float* dis = (float*)(ws + off); off += (size_t)N_NODES * 4;
    int* rowptr = (int*)(ws + off); off += (size_t)(N_NODES + 1) * 4;
    off = (off + 255) & ~(size_t)255;
    int* cursor = (int*)(ws + off); off += (size_t)N_NODES * 4;
    int* blockSums = (int*)(ws + off); off += 256;
    int* blockOffs = (int*)(ws + off); off += 256;
    int* csr_src = (int*)(ws + off); off += (size_t)N_EDGES * 4;
    float* xsp = (float*)(ws + off); off += (size_t)N_NODES * 8 * 4;
    float* aggx = (float*)(ws + off); off += (size_t)N_NODES * F_IN * 4;
    float* normsum = (float*)(ws + off); off += (size_t)N_NODES * 4;
    off = (off + 255) & ~(size_t)255;
    unsigned short* hsA = (unsigned short*)(ws + off); off += (size_t)N_NODES * DIM * 2;
    off = (off + 255) & ~(size_t)255;
    unsigned short* hsB = (unsigned short*)(ws + off); off += (size_t)N_NODES * DIM * 2;
    off = (off + 255) & ~(size_t)255;
    float* hf = (float*)(ws + off); off += (size_t)N_NODES * DIM * 4;
    (void)ws_size;

    float* out = (float*)d_out;                        // [G, F_OUT]
    float* pooled = (float*)d_out + N_GRAPHS * F_OUT;  // [G, 2D]

    // degree + normalization (+ packed xsp = {dis*x, dis})
    hipMemsetAsync(deg, 0, (size_t)N_NODES * 4, stream);
    deg_kernel<<<(N_EDGES + 255) / 256, 256, 0, stream>>>(cols, deg, N_EDGES);
    dis_xs_kernel<<<(N_NODES + 255) / 256, 256, 0, stream>>>(deg, x, dis, xsp, N_NODES);

    // CSR build (src indices only)
    scan_local<<<numScanBlocks, 256, 0, stream>>>(deg, rowptr, blockSums, N_NODES);
    scan_blocks<<<1, 64, 0, stream>>>(blockSums, blockOffs, numScanBlocks);
    add_offsets<<<(N_NODES + 255) / 256, 256, 0, stream>>>(rowptr, cursor, blockOffs, N_NODES);
    fill_csr<<<(N_EDGES + 255) / 256, 256, 0, stream>>>(rows, cols, cursor, csr_src, N_EDGES);

    // Layer 0 (agg on x, 4 lanes/node) + fused lin0+lin1 -> hs1 (bf16, hsA)
    csr_agg_x<<<(N_NODES * 4 + 255) / 256, 256, 0, stream>>>(rowptr, csr_src, xsp, aggx, normsum, N_NODES);
    const int gridW = (N_NODES + 15) / 16;
    lin01_kernel<<<gridW, 256, 0, stream>>>(aggx, normsum, dis, W0, b0, W1, b1, hsA, N_NODES);

    // fused agg+linear chain (bf16 gathers, barrier-free)
    fused_agg_lin<false, true><<<gridW, 256, 0, stream>>>(
        rowptr, csr_src, dis, (const uint2*)hsA, nullptr, W2, b2, (void*)hsB);
    fused_agg_lin<false, true><<<gridW, 256, 0, stream>>>(
        rowptr, csr_src, dis, (const uint2*)hsB, nullptr, W3, b3, (void*)hsA);
    fused_agg_lin<true, false><<<gridW, 256, 0, stream>>>(
        rowptr, csr_src, dis, (const uint2*)hsA, topo, Wf, bf_, (void*)hf);

    // Pooling + output GEMM
    pool_kernel<<<N_GRAPHS, 256, 0, stream>>>(hf, pooled, N_NODES, N_GRAPHS);
    out_kernel<<<(N_GRAPHS * F_OUT + 255) / 256, 256, 0, stream>>>(pooled, Wo, bo, out, N_GRAPHS);
}

// Round 7
// 474.345 us; speedup vs baseline: 1.3255x; 1.3255x over previous
//
#include <hip/hip_runtime.h>
#include <hip/hip_bf16.h>

#define N_NODES 100000
#define N_EDGES 1000000
#define DIM 64
#define N_GRAPHS 256
#define F_IN 4
#define F_OUT 4
#define SCAN_CHUNK 2048  // 256 threads x 8

__device__ __forceinline__ float bf_lo(unsigned int u) { return __uint_as_float(u << 16); }
__device__ __forceinline__ float bf_hi(unsigned int u) { return __uint_as_float(u & 0xffff0000u); }
__device__ __forceinline__ unsigned short f2bf(float f) {
    unsigned int u = __float_as_uint(f);
    u = u + 0x7fffu + ((u >> 16) & 1u);  // RTNE
    return (unsigned short)(u >> 16);
}

// ---------------- degree ----------------
__global__ void deg_kernel(const int* __restrict__ cols, int* __restrict__ deg, int E) {
    int e = blockIdx.x * 256 + threadIdx.x;
    if (e < E) atomicAdd(&deg[cols[e]], 1);
}

// ---------------- dis + packed xsp = {dis*x[0..3], dis, pad3} (32B rows) ----------------
__global__ void dis_xs_kernel(const int* __restrict__ deg, const float* __restrict__ x,
                              float* __restrict__ dis, float* __restrict__ xsp, int n) {
    int i = blockIdx.x * 256 + threadIdx.x;
    if (i >= n) return;
    float d = 1.0f / sqrtf((float)(deg[i] + 1));  // +1 for self loop
    dis[i] = d;
    float4 xi = ((const float4*)x)[i];
    ((float4*)xsp)[2 * i] = make_float4(d * xi.x, d * xi.y, d * xi.z, d * xi.w);
    ((float4*)xsp)[2 * i + 1] = make_float4(d, 0.f, 0.f, 0.f);
}

// ---------------- CSR build ----------------
__global__ void scan_local(const int* __restrict__ deg, int* __restrict__ rowptr,
                           int* __restrict__ blockSums, int n) {
    __shared__ int sh[256];
    int b = blockIdx.x, t = threadIdx.x;
    int base = b * SCAN_CHUNK + t * 8;
    int v[8];
    int s = 0;
#pragma unroll
    for (int i = 0; i < 8; ++i) {
        int idx = base + i;
        int d = (idx < n) ? deg[idx] : 0;
        v[i] = s;
        s += d;
    }
    sh[t] = s;
    __syncthreads();
    for (int ofs = 1; ofs < 256; ofs <<= 1) {
        int u = (t >= ofs) ? sh[t - ofs] : 0;
        __syncthreads();
        sh[t] += u;
        __syncthreads();
    }
    int texcl = sh[t] - s;
#pragma unroll
    for (int i = 0; i < 8; ++i) {
        int idx = base + i;
        if (idx < n) rowptr[idx] = texcl + v[i];
    }
    if (t == 255) blockSums[b] = sh[255];
}

__global__ void scan_blocks(const int* __restrict__ blockSums, int* __restrict__ blockOffs, int nb) {
    int t = threadIdx.x;  // single wave of 64, nb <= 64
    int orig = (t < nb) ? blockSums[t] : 0;
    int v = orig;
    for (int ofs = 1; ofs < 64; ofs <<= 1) {
        int u = __shfl_up(v, ofs, 64);
        if (t >= ofs) v += u;
    }
    if (t < nb) blockOffs[t] = v - orig;  // exclusive
}

__global__ void add_offsets(int* __restrict__ rowptr, int* __restrict__ cursor,
                            const int* __restrict__ blockOffs, int n) {
    int i = blockIdx.x * 256 + threadIdx.x;
    if (i < n) {
        int v = rowptr[i] + blockOffs[i >> 11];  // SCAN_CHUNK = 2048
        rowptr[i] = v;
        cursor[i] = v;
    }
    if (i == 0) rowptr[n] = N_EDGES;
}

__global__ void fill_csr(const int* __restrict__ rows, const int* __restrict__ cols,
                         int* __restrict__ cursor, int* __restrict__ csr_src, int E) {
    int e = blockIdx.x * 256 + threadIdx.x;
    if (e >= E) return;
    int c = cols[e], r = rows[e];
    int pos = atomicAdd(&cursor[c], 1);
    csr_src[pos] = r;
}

// ---------------- layer-0 aggregation: 4 lanes per node, x2 unroll ----------------
__global__ __launch_bounds__(256, 8)
void csr_agg_x(const int* __restrict__ rowptr, const int* __restrict__ csr_src,
               const float* __restrict__ xsp, float* __restrict__ aggx,
               float* __restrict__ normsum, int n) {
    int t = blockIdx.x * 256 + threadIdx.x;
    int c = t >> 2, sl = t & 3;
    if (c >= n) return;
    const float4* p = (const float4*)xsp;
    int s = rowptr[c], e = rowptr[c + 1];
    float4 a = make_float4(0.f, 0.f, 0.f, 0.f);
    float ns = 0.f;
    float dc = p[2 * c + 1].x;
    if (sl == 0) { a = p[2 * c]; ns = dc; }  // self contribution
    int k = s + sl;
    for (; k + 4 < e; k += 8) {
        int r1 = csr_src[k], r2 = csr_src[k + 4];
        float4 v1 = p[2 * r1];
        float n1 = p[2 * r1 + 1].x;
        float4 v2 = p[2 * r2];
        float n2 = p[2 * r2 + 1].x;
        a.x += v1.x + v2.x; a.y += v1.y + v2.y; a.z += v1.z + v2.z; a.w += v1.w + v2.w;
        ns += n1 + n2;
    }
    if (k < e) {
        int r = csr_src[k];
        float4 v = p[2 * r];
        a.x += v.x; a.y += v.y; a.z += v.z; a.w += v.w;
        ns += p[2 * r + 1].x;
    }
#pragma unroll
    for (int m = 1; m < 4; m <<= 1) {
        a.x += __shfl_xor(a.x, m, 64);
        a.y += __shfl_xor(a.y, m, 64);
        a.z += __shfl_xor(a.z, m, 64);
        a.w += __shfl_xor(a.w, m, 64);
        ns += __shfl_xor(ns, m, 64);
    }
    if (sl == 0) {
        ((float4*)aggx)[c] = make_float4(dc * a.x, dc * a.y, dc * a.z, dc * a.w);
        normsum[c] = dc * ns;
    }
}

// ---------------- fused lin0+lin1 -> bf16 hs1 ----------------
__global__ __launch_bounds__(256, 4)
void lin01_kernel(const float* __restrict__ aggx, const float* __restrict__ normsum,
                  const float* __restrict__ dis, const float* __restrict__ W0,
                  const float* __restrict__ b0, const float* __restrict__ W1,
                  const float* __restrict__ b1, unsigned short* __restrict__ out, int n) {
    int tid = threadIdx.x;
    int wid = tid >> 6, j = tid & 63;
    float w0c[4];
#pragma unroll
    for (int k = 0; k < 4; ++k) w0c[k] = W0[k * 64 + j];
    float b0j = b0[j];
    float w1c[64];
#pragma unroll
    for (int k = 0; k < 64; ++k) w1c[k] = W1[k * 64 + j];
    float b1j = b1[j];
    int rowBase = blockIdx.x * 16 + wid * 4;
#pragma unroll 1
    for (int i = 0; i < 4; ++i) {
        int row = rowBase + i;
        if (row >= n) return;
        float4 ax = ((const float4*)aggx)[row];
        float ns = normsum[row];
        float g = ns * b0j + ax.x * w0c[0] + ax.y * w0c[1] + ax.z * w0c[2] + ax.w * w0c[3];
        float t = tanhf(g);
        float o = b1j;
#pragma unroll
        for (int k = 0; k < 64; ++k) o += __shfl(t, k, 64) * w1c[k];
        out[row * 64 + j] = f2bf(dis[row] * o);
    }
}

// ---------------- fused agg (bf16 rows) + linear, wave-independent, barrier-free ----------------
// gcn = dc*(sum hs + self); act = (topo*)tanh(gcn); out = act@W + b (x dc if BF16_OUT)
// NO launch_bounds: r6's (256,6) spilled wcol to scratch (WRITE 25->125MB). r3's
// unconstrained allocation gave VGPR~48, occ ~50% -- let the allocator choose.
template <bool TOPO, bool BF16_OUT>
__global__ void fused_agg_lin(const int* __restrict__ rowptr, const int* __restrict__ csr_src,
                              const float* __restrict__ dis, const uint2* __restrict__ hs,
                              const float* __restrict__ topo, const float* __restrict__ W,
                              const float* __restrict__ b, void* __restrict__ outv) {
    __shared__ float sh[4][64];  // wave-private slice: no block barrier needed
    int tid = threadIdx.x;
    int wid = tid >> 6, lane = tid & 63;
    int q = lane >> 4, f = lane & 15;  // 4 edge slots x 16 lanes (8B each -> 128B row)
    float wcol[64];
#pragma unroll
    for (int k = 0; k < 64; ++k) wcol[k] = W[k * 64 + lane];
    float bj = b[lane];
    int nodeBase = blockIdx.x * 16 + wid * 4;  // grid*16 == N exactly
#pragma unroll 1
    for (int i = 0; i < 4; ++i) {
        int node = nodeBase + i;
        float dc = dis[node];
        int s = rowptr[node], e = rowptr[node + 1];
        float a0 = 0.f, a1 = 0.f, a2 = 0.f, a3 = 0.f;
        float c0 = 0.f, c1 = 0.f, c2 = 0.f, c3 = 0.f;
        if (q == 0) {  // self row (hs pre-scaled by dis)
            uint2 u = hs[node * 16 + f];
            a0 = bf_lo(u.x); a1 = bf_hi(u.x); a2 = bf_lo(u.y); a3 = bf_hi(u.y);
        }
        int k = s + q;
        for (; k + 4 < e; k += 8) {  // x2 unroll: 8 rows in flight per wave
            int r1 = csr_src[k];
            int r2 = csr_src[k + 4];
            uint2 u1 = hs[r1 * 16 + f];
            uint2 u2 = hs[r2 * 16 + f];
            a0 += bf_lo(u1.x); a1 += bf_hi(u1.x); a2 += bf_lo(u1.y); a3 += bf_hi(u1.y);
            c0 += bf_lo(u2.x); c1 += bf_hi(u2.x); c2 += bf_lo(u2.y); c3 += bf_hi(u2.y);
        }
        if (k < e) {
            int r = csr_src[k];
            uint2 u = hs[r * 16 + f];
            a0 += bf_lo(u.x); a1 += bf_hi(u.x); a2 += bf_lo(u.y); a3 += bf_hi(u.y);
        }
        a0 += c0; a1 += c1; a2 += c2; a3 += c3;
#pragma unroll
        for (int m = 16; m < 64; m <<= 1) {
            a0 += __shfl_xor(a0, m, 64);
            a1 += __shfl_xor(a1, m, 64);
            a2 += __shfl_xor(a2, m, 64);
            a3 += __shfl_xor(a3, m, 64);
        }
        if (q == 0) {
            float4 v;
            v.x = tanhf(dc * a0);
            v.y = tanhf(dc * a1);
            v.z = tanhf(dc * a2);
            v.w = tanhf(dc * a3);
            if (TOPO) {
                float4 tp = ((const float4*)topo)[node * 16 + f];
                v.x *= tp.x; v.y *= tp.y; v.z *= tp.z; v.w *= tp.w;
            }
            ((float4*)sh[wid])[f] = v;
        }
        // intra-wave ds_write -> ds_read: ordered via lgkmcnt, no __syncthreads
        float o = bj;
        const float4* shr = (const float4*)sh[wid];
#pragma unroll
        for (int kq = 0; kq < 16; ++kq) {
            float4 v = shr[kq];
            o += v.x * wcol[4 * kq] + v.y * wcol[4 * kq + 1] +
                 v.z * wcol[4 * kq + 2] + v.w * wcol[4 * kq + 3];
        }
        if (BF16_OUT)
            ((unsigned short*)outv)[node * 64 + lane] = f2bf(dc * o);
        else
            ((float*)outv)[node * 64 + lane] = o;
    }
}

// ---------------- per-graph pooling (contiguous sorted batch vector) ----------------
__global__ void pool_kernel(const float* __restrict__ hf, float* __restrict__ pooled, int n, int G) {
    int g = blockIdx.x;
    int start = (int)(((long long)g * n + G - 1) / G);
    int end = (int)(((long long)(g + 1) * n + G - 1) / G);
    int tid = threadIdx.x;
    int nd = tid >> 6, j = tid & 63;
    float mx = -INFINITY, sm = 0.f;
    for (int i = start + nd; i < end; i += 4) {
        float v = hf[i * 64 + j];
        mx = fmaxf(mx, v);
        sm += v;
    }
    __shared__ float smx[256];
    __shared__ float ssm[256];
    smx[tid] = mx;
    ssm[tid] = sm;
    __syncthreads();
    if (nd == 0) {
        mx = fmaxf(fmaxf(smx[j], smx[64 + j]), fmaxf(smx[128 + j], smx[192 + j]));
        sm = ssm[j] + ssm[64 + j] + ssm[128 + j] + ssm[192 + j];
        float cnt = (float)(end - start);
        pooled[g * 128 + j] = mx;
        pooled[g * 128 + 64 + j] = sm / cnt;
    }
}

// ---------------- output GEMM ----------------
__global__ void out_kernel(const float* __restrict__ pooled, const float* __restrict__ Wo,
                           const float* __restrict__ bo, float* __restrict__ out, int G) {
    int tid = blockIdx.x * blockDim.x + threadIdx.x;
    if (tid >= G * F_OUT) return;
    int g = tid >> 2, o = tid & 3;
    float acc = bo[o];
#pragma unroll 8
    for (int k = 0; k < 2 * DIM; ++k) acc += pooled[g * 2 * DIM + k] * Wo[k * F_OUT + o];
    out[g * F_OUT + o] = acc;
}

extern "C" void kernel_launch(void* const* d_in, const int* in_sizes, int n_in,
                              void* d_out, int out_size, void* d_ws, size_t ws_size,
                              hipStream_t stream) {
    const float* x = (const float*)d_in[0];
    const int* edge_index = (const int*)d_in[1];
    const float* topo = (const float*)d_in[3];
    const float* W0 = (const float*)d_in[4];
    const float* b0 = (const float*)d_in[5];
    const float* W1 = (const float*)d_in[6];
    const float* b1 = (const float*)d_in[7];
    const float* W2 = (const float*)d_in[8];
    const float* b2 = (const float*)d_in[9];
    const float* W3 = (const float*)d_in[10];
    const float* b3 = (const float*)d_in[11];
    const float* Wf = (const float*)d_in[12];
    const float* bf_ = (const float*)d_in[13];
    const float* Wo = (const float*)d_in[14];
    const float* bo = (const float*)d_in[15];

    const int* rows = edge_index;            // sources
    const int* cols = edge_index + N_EDGES;  // targets

    const int numScanBlocks = (N_NODES + SCAN_CHUNK - 1) / SCAN_CHUNK;  // 49

    // workspace layout
    char* ws = (char*)d_ws;
    size_t off = 0;
    int* deg = (int*)(ws + off); off += (size_t)N_NODES * 4;
    float* dis = (float*)(ws + off); off += (size_t)N_NODES * 4;
    int* rowptr = (int*)(ws + off); off += (size_t)(N_NODES + 1) * 4;
    off = (off + 255) & ~(size_t)255;
    int* cursor = (int*)(ws + off); off += (size_t)N_NODES * 4;
    int* blockSums = (int*)(ws + off); off += 256;
    int* blockOffs = (int*)(ws + off); off += 256;
    int* csr_src = (int*)(ws + off); off += (size_t)N_EDGES * 4;
    float* xsp = (float*)(ws + off); off += (size_t)N_NODES * 8 * 4;
    float* aggx = (float*)(ws + off); off += (size_t)N_NODES * F_IN * 4;
    float* normsum = (float*)(ws + off); off += (size_t)N_NODES * 4;
    off = (off + 255) & ~(size_t)255;
    unsigned short* hsA = (unsigned short*)(ws + off); off += (size_t)N_NODES * DIM * 2;
    off = (off + 255) & ~(size_t)255;
    unsigned short* hsB = (unsigned short*)(ws + off); off += (size_t)N_NODES * DIM * 2;
    off = (off + 255) & ~(size_t)255;
    float* hf = (float*)(ws + off); off += (size_t)N_NODES * DIM * 4;
    (void)ws_size;

    float* out = (float*)d_out;                        // [G, F_OUT]
    float* pooled = (float*)d_out + N_GRAPHS * F_OUT;  // [G, 2D]

    // degree + normalization (+ packed xsp = {dis*x, dis})
    hipMemsetAsync(deg, 0, (size_t)N_NODES * 4, stream);
    deg_kernel<<<(N_EDGES + 255) / 256, 256, 0, stream>>>(cols, deg, N_EDGES);
    dis_xs_kernel<<<(N_NODES + 255) / 256, 256, 0, stream>>>(deg, x, dis, xsp, N_NODES);

    // CSR build (src indices only)
    scan_local<<<numScanBlocks, 256, 0, stream>>>(deg, rowptr, blockSums, N_NODES);
    scan_blocks<<<1, 64, 0, stream>>>(blockSums, blockOffs, numScanBlocks);
    add_offsets<<<(N_NODES + 255) / 256, 256, 0, stream>>>(rowptr, cursor, blockOffs, N_NODES);
    fill_csr<<<(N_EDGES + 255) / 256, 256, 0, stream>>>(rows, cols, cursor, csr_src, N_EDGES);

    // Layer 0 (agg on x, 4 lanes/node) + fused lin0+lin1 -> hs1 (bf16, hsA)
    csr_agg_x<<<(N_NODES * 4 + 255) / 256, 256, 0, stream>>>(rowptr, csr_src, xsp, aggx, normsum, N_NODES);
    const int gridW = (N_NODES + 15) / 16;
    lin01_kernel<<<gridW, 256, 0, stream>>>(aggx, normsum, dis, W0, b0, W1, b1, hsA, N_NODES);

    // fused agg+linear chain (bf16 gathers, barrier-free)
    fused_agg_lin<false, true><<<gridW, 256, 0, stream>>>(
        rowptr, csr_src, dis, (const uint2*)hsA, nullptr, W2, b2, (void*)hsB);
    fused_agg_lin<false, true><<<gridW, 256, 0, stream>>>(
        rowptr, csr_src, dis, (const uint2*)hsB, nullptr, W3, b3, (void*)hsA);
    fused_agg_lin<true, false><<<gridW, 256, 0, stream>>>(
        rowptr, csr_src, dis, (const uint2*)hsA, topo, Wf, bf_, (void*)hf);

    // Pooling + output GEMM
    pool_kernel<<<N_GRAPHS, 256, 0, stream>>>(hf, pooled, N_NODES, N_GRAPHS);
    out_kernel<<<(N_GRAPHS * F_OUT + 255) / 256, 256, 0, stream>>>(pooled, Wo, bo, out, N_GRAPHS);
}

// Round 8
// 454.702 us; speedup vs baseline: 1.3828x; 1.0432x over previous
//
#include <hip/hip_runtime.h>
#include <hip/hip_bf16.h>

#define N_NODES 100000
#define N_EDGES 1000000
#define DIM 64
#define N_GRAPHS 256
#define F_IN 4
#define F_OUT 4
#define SCAN_CHUNK 2048  // 256 threads x 8

__device__ __forceinline__ float bf_lo(unsigned int u) { return __uint_as_float(u << 16); }
__device__ __forceinline__ float bf_hi(unsigned int u) { return __uint_as_float(u & 0xffff0000u); }
__device__ __forceinline__ unsigned short f2bf(float f) {
    unsigned int u = __float_as_uint(f);
    u = u + 0x7fffu + ((u >> 16) & 1u);  // RTNE
    return (unsigned short)(u >> 16);
}

__device__ __forceinline__ void acc_row8(float* a, uint4 u) {
    a[0] += bf_lo(u.x); a[1] += bf_hi(u.x);
    a[2] += bf_lo(u.y); a[3] += bf_hi(u.y);
    a[4] += bf_lo(u.z); a[5] += bf_hi(u.z);
    a[6] += bf_lo(u.w); a[7] += bf_hi(u.w);
}

// ---------------- degree ----------------
__global__ void deg_kernel(const int* __restrict__ cols, int* __restrict__ deg, int E) {
    int e = blockIdx.x * 256 + threadIdx.x;
    if (e < E) atomicAdd(&deg[cols[e]], 1);
}

// ---------------- dis + packed xsp = {dis*x[0..3], dis, pad3} (32B rows) ----------------
__global__ void dis_xs_kernel(const int* __restrict__ deg, const float* __restrict__ x,
                              float* __restrict__ dis, float* __restrict__ xsp, int n) {
    int i = blockIdx.x * 256 + threadIdx.x;
    if (i >= n) return;
    float d = 1.0f / sqrtf((float)(deg[i] + 1));  // +1 for self loop
    dis[i] = d;
    float4 xi = ((const float4*)x)[i];
    ((float4*)xsp)[2 * i] = make_float4(d * xi.x, d * xi.y, d * xi.z, d * xi.w);
    ((float4*)xsp)[2 * i + 1] = make_float4(d, 0.f, 0.f, 0.f);
}

// ---------------- CSR build ----------------
__global__ void scan_local(const int* __restrict__ deg, int* __restrict__ rowptr,
                           int* __restrict__ blockSums, int n) {
    __shared__ int sh[256];
    int b = blockIdx.x, t = threadIdx.x;
    int base = b * SCAN_CHUNK + t * 8;
    int v[8];
    int s = 0;
#pragma unroll
    for (int i = 0; i < 8; ++i) {
        int idx = base + i;
        int d = (idx < n) ? deg[idx] : 0;
        v[i] = s;
        s += d;
    }
    sh[t] = s;
    __syncthreads();
    for (int ofs = 1; ofs < 256; ofs <<= 1) {
        int u = (t >= ofs) ? sh[t - ofs] : 0;
        __syncthreads();
        sh[t] += u;
        __syncthreads();
    }
    int texcl = sh[t] - s;
#pragma unroll
    for (int i = 0; i < 8; ++i) {
        int idx = base + i;
        if (idx < n) rowptr[idx] = texcl + v[i];
    }
    if (t == 255) blockSums[b] = sh[255];
}

__global__ void scan_blocks(const int* __restrict__ blockSums, int* __restrict__ blockOffs, int nb) {
    int t = threadIdx.x;  // single wave of 64, nb <= 64
    int orig = (t < nb) ? blockSums[t] : 0;
    int v = orig;
    for (int ofs = 1; ofs < 64; ofs <<= 1) {
        int u = __shfl_up(v, ofs, 64);
        if (t >= ofs) v += u;
    }
    if (t < nb) blockOffs[t] = v - orig;  // exclusive
}

__global__ void add_offsets(int* __restrict__ rowptr, int* __restrict__ cursor,
                            const int* __restrict__ blockOffs, int n) {
    int i = blockIdx.x * 256 + threadIdx.x;
    if (i < n) {
        int v = rowptr[i] + blockOffs[i >> 11];  // SCAN_CHUNK = 2048
        rowptr[i] = v;
        cursor[i] = v;
    }
    if (i == 0) rowptr[n] = N_EDGES;
}

__global__ void fill_csr(const int* __restrict__ rows, const int* __restrict__ cols,
                         int* __restrict__ cursor, int* __restrict__ csr_src, int E) {
    int e = blockIdx.x * 256 + threadIdx.x;
    if (e >= E) return;
    int c = cols[e], r = rows[e];
    int pos = atomicAdd(&cursor[c], 1);
    csr_src[pos] = r;
}

// ---------------- layer-0 aggregation: 4 lanes per node, x2 unroll ----------------
__global__ __launch_bounds__(256, 8)
void csr_agg_x(const int* __restrict__ rowptr, const int* __restrict__ csr_src,
               const float* __restrict__ xsp, float* __restrict__ aggx,
               float* __restrict__ normsum, int n) {
    int t = blockIdx.x * 256 + threadIdx.x;
    int c = t >> 2, sl = t & 3;
    if (c >= n) return;
    const float4* p = (const float4*)xsp;
    int s = rowptr[c], e = rowptr[c + 1];
    float4 a = make_float4(0.f, 0.f, 0.f, 0.f);
    float ns = 0.f;
    float dc = p[2 * c + 1].x;
    if (sl == 0) { a = p[2 * c]; ns = dc; }  // self contribution
    int k = s + sl;
    for (; k + 4 < e; k += 8) {
        int r1 = csr_src[k], r2 = csr_src[k + 4];
        float4 v1 = p[2 * r1];
        float n1 = p[2 * r1 + 1].x;
        float4 v2 = p[2 * r2];
        float n2 = p[2 * r2 + 1].x;
        a.x += v1.x + v2.x; a.y += v1.y + v2.y; a.z += v1.z + v2.z; a.w += v1.w + v2.w;
        ns += n1 + n2;
    }
    if (k < e) {
        int r = csr_src[k];
        float4 v = p[2 * r];
        a.x += v.x; a.y += v.y; a.z += v.z; a.w += v.w;
        ns += p[2 * r + 1].x;
    }
#pragma unroll
    for (int m = 1; m < 4; m <<= 1) {
        a.x += __shfl_xor(a.x, m, 64);
        a.y += __shfl_xor(a.y, m, 64);
        a.z += __shfl_xor(a.z, m, 64);
        a.w += __shfl_xor(a.w, m, 64);
        ns += __shfl_xor(ns, m, 64);
    }
    if (sl == 0) {
        ((float4*)aggx)[c] = make_float4(dc * a.x, dc * a.y, dc * a.z, dc * a.w);
        normsum[c] = dc * ns;
    }
}

// ---------------- fused lin0+lin1 -> bf16 hs1 (LDS broadcast epilogue) ----------------
__global__ __launch_bounds__(256, 4)
void lin01_kernel(const float* __restrict__ aggx, const float* __restrict__ normsum,
                  const float* __restrict__ dis, const float* __restrict__ W0,
                  const float* __restrict__ b0, const float* __restrict__ W1,
                  const float* __restrict__ b1, unsigned short* __restrict__ out, int n) {
    __shared__ float sh[4][64];
    int tid = threadIdx.x;
    int wid = tid >> 6, j = tid & 63;
    float w0c[4];
#pragma unroll
    for (int k = 0; k < 4; ++k) w0c[k] = W0[k * 64 + j];
    float b0j = b0[j];
    float w1c[64];
#pragma unroll
    for (int k = 0; k < 64; ++k) w1c[k] = W1[k * 64 + j];
    float b1j = b1[j];
    int rowBase = blockIdx.x * 16 + wid * 4;
#pragma unroll 1
    for (int i = 0; i < 4; ++i) {
        int row = rowBase + i;
        if (row >= n) return;
        float4 ax = ((const float4*)aggx)[row];
        float ns = normsum[row];
        float g = ns * b0j + ax.x * w0c[0] + ax.y * w0c[1] + ax.z * w0c[2] + ax.w * w0c[3];
        sh[wid][j] = tanhf(g);
        float o = b1j;
        const float4* shr = (const float4*)sh[wid];
#pragma unroll
        for (int kq = 0; kq < 16; ++kq) {
            float4 v = shr[kq];
            o += v.x * w1c[4 * kq] + v.y * w1c[4 * kq + 1] +
                 v.z * w1c[4 * kq + 2] + v.w * w1c[4 * kq + 3];
        }
        out[row * 64 + j] = f2bf(dis[row] * o);
    }
}

// ---------------- fused agg (bf16 rows, 8 slots x 8 lanes x uint4) + linear ----------------
// One load instruction covers 8 different rows (1KB in flight). gcn = dc*(sum hs + self);
// act = (topo*)tanh(gcn); out = act@W + b (x dc if BF16_OUT). Barrier-free (wave-private LDS).
// NO launch_bounds: r6's (256,6) spilled wcol to scratch (WRITE 25->125MB).
template <bool TOPO, bool BF16_OUT>
__global__ void fused_agg_lin(const int* __restrict__ rowptr, const int* __restrict__ csr_src,
                              const float* __restrict__ dis, const uint4* __restrict__ hs,
                              const float* __restrict__ topo, const float* __restrict__ W,
                              const float* __restrict__ b, void* __restrict__ outv) {
    __shared__ float sh[4][64];  // wave-private slice
    int tid = threadIdx.x;
    int wid = tid >> 6, lane = tid & 63;
    int q = lane >> 3, f = lane & 7;  // 8 edge slots x 8 lanes (16B each -> 128B row)
    float wcol[64];
#pragma unroll
    for (int k = 0; k < 64; ++k) wcol[k] = W[k * 64 + lane];
    float bj = b[lane];
    int nodeBase = blockIdx.x * 16 + wid * 4;  // grid*16 == N exactly
#pragma unroll 1
    for (int i = 0; i < 4; ++i) {
        int node = nodeBase + i;
        float dc = dis[node];
        int s = rowptr[node], e = rowptr[node + 1];
        float a[8];
#pragma unroll
        for (int c = 0; c < 8; ++c) a[c] = 0.f;
        if (q == 0) acc_row8(a, hs[node * 8 + f]);  // self (hs pre-scaled by dis)
        for (int k = s + q; k < e; k += 8) {
            int r = csr_src[k];
            acc_row8(a, hs[r * 8 + f]);
        }
#pragma unroll
        for (int m = 8; m < 64; m <<= 1) {
#pragma unroll
            for (int c = 0; c < 8; ++c) a[c] += __shfl_xor(a[c], m, 64);
        }
        if (q == 0) {  // lanes 0..7 hold elements [8f, 8f+8)
            float4 v0, v1;
            v0.x = tanhf(dc * a[0]); v0.y = tanhf(dc * a[1]);
            v0.z = tanhf(dc * a[2]); v0.w = tanhf(dc * a[3]);
            v1.x = tanhf(dc * a[4]); v1.y = tanhf(dc * a[5]);
            v1.z = tanhf(dc * a[6]); v1.w = tanhf(dc * a[7]);
            if (TOPO) {
                float4 t0 = ((const float4*)topo)[node * 16 + 2 * f];
                float4 t1 = ((const float4*)topo)[node * 16 + 2 * f + 1];
                v0.x *= t0.x; v0.y *= t0.y; v0.z *= t0.z; v0.w *= t0.w;
                v1.x *= t1.x; v1.y *= t1.y; v1.z *= t1.z; v1.w *= t1.w;
            }
            ((float4*)sh[wid])[2 * f] = v0;
            ((float4*)sh[wid])[2 * f + 1] = v1;
        }
        // intra-wave ds_write -> ds_read: ordered via lgkmcnt, no __syncthreads
        float o = bj;
        const float4* shr = (const float4*)sh[wid];
#pragma unroll
        for (int kq = 0; kq < 16; ++kq) {
            float4 v = shr[kq];
            o += v.x * wcol[4 * kq] + v.y * wcol[4 * kq + 1] +
                 v.z * wcol[4 * kq + 2] + v.w * wcol[4 * kq + 3];
        }
        if (BF16_OUT)
            ((unsigned short*)outv)[node * 64 + lane] = f2bf(dc * o);
        else
            ((float*)outv)[node * 64 + lane] = o;
    }
}

// ---------------- per-graph pooling (contiguous sorted batch vector) ----------------
__global__ void pool_kernel(const float* __restrict__ hf, float* __restrict__ pooled, int n, int G) {
    int g = blockIdx.x;
    int start = (int)(((long long)g * n + G - 1) / G);
    int end = (int)(((long long)(g + 1) * n + G - 1) / G);
    int tid = threadIdx.x;
    int nd = tid >> 6, j = tid & 63;
    float mx = -INFINITY, sm = 0.f;
    for (int i = start + nd; i < end; i += 4) {
        float v = hf[i * 64 + j];
        mx = fmaxf(mx, v);
        sm += v;
    }
    __shared__ float smx[256];
    __shared__ float ssm[256];
    smx[tid] = mx;
    ssm[tid] = sm;
    __syncthreads();
    if (nd == 0) {
        mx = fmaxf(fmaxf(smx[j], smx[64 + j]), fmaxf(smx[128 + j], smx[192 + j]));
        sm = ssm[j] + ssm[64 + j] + ssm[128 + j] + ssm[192 + j];
        float cnt = (float)(end - start);
        pooled[g * 128 + j] = mx;
        pooled[g * 128 + 64 + j] = sm / cnt;
    }
}

// ---------------- output GEMM ----------------
__global__ void out_kernel(const float* __restrict__ pooled, const float* __restrict__ Wo,
                           const float* __restrict__ bo, float* __restrict__ out, int G) {
    int tid = blockIdx.x * blockDim.x + threadIdx.x;
    if (tid >= G * F_OUT) return;
    int g = tid >> 2, o = tid & 3;
    float acc = bo[o];
#pragma unroll 8
    for (int k = 0; k < 2 * DIM; ++k) acc += pooled[g * 2 * DIM + k] * Wo[k * F_OUT + o];
    out[g * F_OUT + o] = acc;
}

extern "C" void kernel_launch(void* const* d_in, const int* in_sizes, int n_in,
                              void* d_out, int out_size, void* d_ws, size_t ws_size,
                              hipStream_t stream) {
    const float* x = (const float*)d_in[0];
    const int* edge_index = (const int*)d_in[1];
    const float* topo = (const float*)d_in[3];
    const float* W0 = (const float*)d_in[4];
    const float* b0 = (const float*)d_in[5];
    const float* W1 = (const float*)d_in[6];
    const float* b1 = (const float*)d_in[7];
    const float* W2 = (const float*)d_in[8];
    const float* b2 = (const float*)d_in[9];
    const float* W3 = (const float*)d_in[10];
    const float* b3 = (const float*)d_in[11];
    const float* Wf = (const float*)d_in[12];
    const float* bf_ = (const float*)d_in[13];
    const float* Wo = (const float*)d_in[14];
    const float* bo = (const float*)d_in[15];

    const int* rows = edge_index;            // sources
    const int* cols = edge_index + N_EDGES;  // targets

    const int numScanBlocks = (N_NODES + SCAN_CHUNK - 1) / SCAN_CHUNK;  // 49

    // workspace layout
    char* ws = (char*)d_ws;
    size_t off = 0;
    int* deg = (int*)(ws + off); off += (size_t)N_NODES * 4;
    float* dis = (float*)(ws + off); off += (size_t)N_NODES * 4;
    int* rowptr = (int*)(ws + off); off += (size_t)(N_NODES + 1) * 4;
    off = (off + 255) & ~(size_t)255;
    int* cursor = (int*)(ws + off); off += (size_t)N_NODES * 4;
    int* blockSums = (int*)(ws + off); off += 256;
    int* blockOffs = (int*)(ws + off); off += 256;
    int* csr_src = (int*)(ws + off); off += (size_t)N_EDGES * 4;
    float* xsp = (float*)(ws + off); off += (size_t)N_NODES * 8 * 4;
    float* aggx = (float*)(ws + off); off += (size_t)N_NODES * F_IN * 4;
    float* normsum = (float*)(ws + off); off += (size_t)N_NODES * 4;
    off = (off + 255) & ~(size_t)255;
    unsigned short* hsA = (unsigned short*)(ws + off); off += (size_t)N_NODES * DIM * 2;
    off = (off + 255) & ~(size_t)255;
    unsigned short* hsB = (unsigned short*)(ws + off); off += (size_t)N_NODES * DIM * 2;
    off = (off + 255) & ~(size_t)255;
    float* hf = (float*)(ws + off); off += (size_t)N_NODES * DIM * 4;
    (void)ws_size;

    float* out = (float*)d_out;                        // [G, F_OUT]
    float* pooled = (float*)d_out + N_GRAPHS * F_OUT;  // [G, 2D]

    // degree + normalization (+ packed xsp = {dis*x, dis})
    hipMemsetAsync(deg, 0, (size_t)N_NODES * 4, stream);
    deg_kernel<<<(N_EDGES + 255) / 256, 256, 0, stream>>>(cols, deg, N_EDGES);
    dis_xs_kernel<<<(N_NODES + 255) / 256, 256, 0, stream>>>(deg, x, dis, xsp, N_NODES);

    // CSR build (src indices only)
    scan_local<<<numScanBlocks, 256, 0, stream>>>(deg, rowptr, blockSums, N_NODES);
    scan_blocks<<<1, 64, 0, stream>>>(blockSums, blockOffs, numScanBlocks);
    add_offsets<<<(N_NODES + 255) / 256, 256, 0, stream>>>(rowptr, cursor, blockOffs, N_NODES);
    fill_csr<<<(N_EDGES + 255) / 256, 256, 0, stream>>>(rows, cols, cursor, csr_src, N_EDGES);

    // Layer 0 (agg on x, 4 lanes/node) + fused lin0+lin1 -> hs1 (bf16, hsA)
    csr_agg_x<<<(N_NODES * 4 + 255) / 256, 256, 0, stream>>>(rowptr, csr_src, xsp, aggx, normsum, N_NODES);
    const int gridW = (N_NODES + 15) / 16;
    lin01_kernel<<<gridW, 256, 0, stream>>>(aggx, normsum, dis, W0, b0, W1, b1, hsA, N_NODES);

    // fused agg+linear chain (bf16 gathers, 8-slot uint4, barrier-free)
    fused_agg_lin<false, true><<<gridW, 256, 0, stream>>>(
        rowptr, csr_src, dis, (const uint4*)hsA, nullptr, W2, b2, (void*)hsB);
    fused_agg_lin<false, true><<<gridW, 256, 0, stream>>>(
        rowptr, csr_src, dis, (const uint4*)hsB, nullptr, W3, b3, (void*)hsA);
    fused_agg_lin<true, false><<<gridW, 256, 0, stream>>>(
        rowptr, csr_src, dis, (const uint4*)hsA, topo, Wf, bf_, (void*)hf);

    // Pooling + output GEMM
    pool_kernel<<<N_GRAPHS, 256, 0, stream>>>(hf, pooled, N_NODES, N_GRAPHS);
    out_kernel<<<(N_GRAPHS * F_OUT + 255) / 256, 256, 0, stream>>>(pooled, Wo, bo, out, N_GRAPHS);
}